// Round 2
// baseline (5380.924 us; speedup 1.0000x reference)
//
#include <hip/hip_runtime.h>

#define B_ 8
#define S_ 1024
#define D_ 512
#define H_ 8
#define HD_ 64
#define F_ 2048

typedef unsigned short u16;  // bf16 bit pattern

__device__ __forceinline__ float bf2f(u16 u) {
  union { unsigned int i; float f; } v; v.i = ((unsigned int)u) << 16; return v.f;
}
__device__ __forceinline__ u16 f2bf(float f) {
  union { float f; unsigned int i; } v; v.f = f;
  unsigned int r = v.i + 0x7fffu + ((v.i >> 16) & 1u);  // round-nearest-even
  return (u16)(r >> 16);
}

// ---------------- RMSNorm: one block per row of 512 ----------------
// IN_BF16=0: x is fp32 (model input). IN_BF16=1: x is internal bf16.
template <int IN_BF16>
__global__ __launch_bounds__(256) void rmsnorm_k(const void* __restrict__ xv,
                                                 const float* __restrict__ w,
                                                 u16* __restrict__ out) {
  int row = blockIdx.x;
  int tid = threadIdx.x;
  float x0, x1;
  if (IN_BF16) {
    const u16* xr = (const u16*)xv + (size_t)row * D_;
    x0 = bf2f(xr[tid]); x1 = bf2f(xr[tid + 256]);
  } else {
    const float* xr = (const float*)xv + (size_t)row * D_;
    x0 = xr[tid]; x1 = xr[tid + 256];
  }
  float s = x0 * x0 + x1 * x1;
#pragma unroll
  for (int off = 32; off >= 1; off >>= 1) s += __shfl_xor(s, off, 64);
  __shared__ float red[4];
  int lane = tid & 63, wid = tid >> 6;
  if (lane == 0) red[wid] = s;
  __syncthreads();
  float tot = red[0] + red[1] + red[2] + red[3];
  float inv = rsqrtf(tot * (1.0f / D_) + 1e-6f);
  u16* orow = out + (size_t)row * D_;
  orow[tid]       = f2bf(x0 * inv * w[tid]);
  orow[tid + 256] = f2bf(x1 * inv * w[tid + 256]);
}

// ------------- Generic GEMM, B-transposed form -------------
// C[m,n] = resid + act( sum_k A[m,k] * W[n,k] )
// A: [M,K] bf16 (internal), W: [N,K] fp32 (model weight)
// RMODE: 0 = no residual, 1 = fp32 residual, 2 = bf16 residual
// OF32:  0 = bf16 output,  1 = fp32 output
// 64x64 tile, BK=16, 256 threads, 4x4 per-thread microtile, fp32 accum.
template <int RELU, int RMODE, int OF32>
__global__ __launch_bounds__(256) void gemm_bt_k(const u16* __restrict__ A,
                                                 const float* __restrict__ W,
                                                 const void* __restrict__ Rv,
                                                 void* __restrict__ Cv,
                                                 int M, int N, int K) {
  __shared__ float As[16][65];  // [k][m], +1 pad
  __shared__ float Ws[16][65];  // [k][n]
  int tid = threadIdx.x;
  int m0 = blockIdx.y * 64, n0 = blockIdx.x * 64;
  int r  = tid >> 2;          // 0..63
  int c4 = (tid & 3) * 4;     // 0,4,8,12
  int tx = tid & 15, ty = tid >> 4;
  float acc[4][4] = {};
  for (int k0 = 0; k0 < K; k0 += 16) {
    const u16*   ap = A + (size_t)(m0 + r) * K + (k0 + c4);
    const float* wp = W + (size_t)(n0 + r) * K + (k0 + c4);
    uint2  av = *(const uint2*)ap;
    float4 wv = *(const float4*)wp;
    As[c4 + 0][r] = bf2f((u16)(av.x & 0xffffu));
    As[c4 + 1][r] = bf2f((u16)(av.x >> 16));
    As[c4 + 2][r] = bf2f((u16)(av.y & 0xffffu));
    As[c4 + 3][r] = bf2f((u16)(av.y >> 16));
    Ws[c4 + 0][r] = wv.x;
    Ws[c4 + 1][r] = wv.y;
    Ws[c4 + 2][r] = wv.z;
    Ws[c4 + 3][r] = wv.w;
    __syncthreads();
#pragma unroll
    for (int kk = 0; kk < 16; kk++) {
      float a[4], b[4];
#pragma unroll
      for (int i = 0; i < 4; i++) a[i] = As[kk][ty * 4 + i];
#pragma unroll
      for (int j = 0; j < 4; j++) b[j] = Ws[kk][tx * 4 + j];
#pragma unroll
      for (int i = 0; i < 4; i++)
#pragma unroll
        for (int j = 0; j < 4; j++) acc[i][j] += a[i] * b[j];
    }
    __syncthreads();
  }
#pragma unroll
  for (int i = 0; i < 4; i++) {
    size_t base = (size_t)(m0 + ty * 4 + i) * N + (n0 + tx * 4);
#pragma unroll
    for (int j = 0; j < 4; j++) {
      float v = acc[i][j];
      if (RELU) v = fmaxf(v, 0.0f);
      if (RMODE == 1) v += ((const float*)Rv)[base + j];
      if (RMODE == 2) v += bf2f(((const u16*)Rv)[base + j]);
      if (OF32) ((float*)Cv)[base + j] = v;
      else      ((u16*)Cv)[base + j]   = f2bf(v);
    }
  }
}

// ------------- Flash-style attention -------------
// One wave per query row (4 rows per 256-thread block).
// Q,K,V: bf16 [B,S,D] with head h at columns h*64..h*64+63.
// bias: fp32 [B,H,S,S]. Online softmax over 64-key chunks.
__global__ __launch_bounds__(256) void attn_k(const u16* __restrict__ Q,
                                              const u16* __restrict__ Km,
                                              const u16* __restrict__ V,
                                              const float* __restrict__ bias,
                                              u16* __restrict__ ctx) {
  int w = threadIdx.x >> 6, lane = threadIdx.x & 63;
  int qrow = blockIdx.x * 4 + w;
  int h = blockIdx.y, b = blockIdx.z;
  __shared__ float qs[4][64];
  size_t qoff = ((size_t)(b * S_ + qrow)) * D_ + h * HD_;
  qs[w][lane] = bf2f(Q[qoff + lane]);
  __syncthreads();
  float m = -1e30f, l = 0.0f, acc = 0.0f;
  const float* bp = bias + (((size_t)(b * H_ + h) * S_) + qrow) * S_;
  for (int kt = 0; kt < S_; kt += 64) {
    int key = kt + lane;
    const u16* kp = Km + ((size_t)(b * S_ + key)) * D_ + h * HD_;
    float s = bp[key];
#pragma unroll
    for (int d8 = 0; d8 < 8; d8++) {
      uint4 kv = *(const uint4*)(kp + d8 * 8);
      unsigned int uu[4] = {kv.x, kv.y, kv.z, kv.w};
#pragma unroll
      for (int q2 = 0; q2 < 4; q2++) {
        s += qs[w][d8 * 8 + q2 * 2]     * bf2f((u16)(uu[q2] & 0xffffu));
        s += qs[w][d8 * 8 + q2 * 2 + 1] * bf2f((u16)(uu[q2] >> 16));
      }
    }
    float Mx = s;
#pragma unroll
    for (int off = 32; off >= 1; off >>= 1) Mx = fmaxf(Mx, __shfl_xor(Mx, off, 64));
    float newm = fmaxf(m, Mx);
    float p = __expf(s - newm);
    float P = p;
#pragma unroll
    for (int off = 32; off >= 1; off >>= 1) P += __shfl_xor(P, off, 64);
    float alpha = __expf(m - newm);
    l = l * alpha + P;
    acc *= alpha;
    const u16* vp = V + ((size_t)(b * S_ + kt)) * D_ + h * HD_ + lane;
#pragma unroll
    for (int j = 0; j < 64; j++) {
      float pj = __shfl(p, j, 64);
      acc += pj * bf2f(vp[(size_t)j * D_]);
    }
    m = newm;
  }
  ctx[qoff + lane] = f2bf(acc / l);
}

extern "C" void kernel_launch(void* const* d_in, const int* in_sizes, int n_in,
                              void* d_out, int out_size, void* d_ws, size_t ws_size,
                              hipStream_t stream) {
  const float* Wk   = (const float*)d_in[0];  // primals_1 [D,D] -> K proj
  const float* Wo   = (const float*)d_in[1];  // primals_2 [D,D] -> out proj
  const float* Wq   = (const float*)d_in[2];  // primals_3 [D,D] -> Q proj
  const float* Wv   = (const float*)d_in[3];  // primals_4 [D,D] -> V proj
  const float* g1   = (const float*)d_in[4];  // primals_5 [D]
  const float* Wf1  = (const float*)d_in[5];  // primals_6 [F,D]
  const float* Wf2  = (const float*)d_in[6];  // primals_7 [D,F]
  const float* g2   = (const float*)d_in[7];  // primals_8 [D]
  const float* X    = (const float*)d_in[8];  // primals_9 [B,S,D] fp32
  const float* bias = (const float*)d_in[9];  // primals_10 [B,H,S,S] fp32
  float* out = (float*)d_out;

  const size_t MD = (size_t)B_ * S_ * D_;  // 4,194,304 elems
  // Workspace layout (bf16 internals), total 5 * 8.39 MB = 41.9 MB:
  u16* h   = (u16*)d_ws;   // buf0: h, later h2
  u16* q   = h + MD;       // buf1: q
  u16* k   = q + MD;       // buf2: k, later x1
  u16* v   = k + MD;       // buf3: v
  u16* ctx = v + MD;       // buf4: ctx, later ff chunk (2048 x 2048 = 4.19M elems)
  u16* x1  = k;            // reuse (k dead after attn)
  u16* h2  = h;            // reuse (h dead after qkv)
  u16* ff  = ctx;          // reuse (ctx dead after out-proj)

  dim3 blk(256);
  const int M = B_ * S_;

  // h = rmsnorm(x, g1)
  rmsnorm_k<0><<<M, blk, 0, stream>>>(X, g1, h);

  // q/k/v = h @ W^T   (bf16 out)
  dim3 g512(D_ / 64, M / 64);
  gemm_bt_k<0, 0, 0><<<g512, blk, 0, stream>>>(h, Wq, nullptr, q, M, D_, D_);
  gemm_bt_k<0, 0, 0><<<g512, blk, 0, stream>>>(h, Wk, nullptr, k, M, D_, D_);
  gemm_bt_k<0, 0, 0><<<g512, blk, 0, stream>>>(h, Wv, nullptr, v, M, D_, D_);

  // ctx = softmax(q k^T + bias) v
  dim3 ga(S_ / 4, H_, B_);
  attn_k<<<ga, blk, 0, stream>>>(q, k, v, bias, ctx);

  // x1 = x + ctx @ Wo^T   (fp32 residual, bf16 out)
  gemm_bt_k<0, 1, 0><<<g512, blk, 0, stream>>>(ctx, Wo, X, x1, M, D_, D_);

  // h2 = rmsnorm(x1, g2)  (bf16 in, bf16 out)
  rmsnorm_k<1><<<M, blk, 0, stream>>>(x1, g2, h2);

  // FFN in 4 chunks of MC rows to keep ws small:
  const int MC = M / 4;  // 2048
  dim3 gff1(F_ / 64, MC / 64);
  dim3 gff2(D_ / 64, MC / 64);
  for (int c = 0; c < 4; c++) {
    const u16* h2c = h2 + (size_t)c * MC * D_;
    const u16* x1c = x1 + (size_t)c * MC * D_;
    float*     oc  = out + (size_t)c * MC * D_;
    // ff = relu(h2 @ Wf1^T)   (bf16 out)
    gemm_bt_k<1, 0, 0><<<gff1, blk, 0, stream>>>(h2c, Wf1, nullptr, ff, MC, F_, D_);
    // out = x1 + ff @ Wf2^T   (bf16 residual, fp32 out)
    gemm_bt_k<0, 2, 1><<<gff2, blk, 0, stream>>>(ff, Wf2, x1c, oc, MC, D_, F_);
  }
}

// Round 3
// 1731.870 us; speedup vs baseline: 3.1070x; 3.1070x over previous
//
#include <hip/hip_runtime.h>

#define B_ 8
#define S_ 1024
#define D_ 512
#define H_ 8
#define HD_ 64
#define F_ 2048

typedef unsigned short u16;  // bf16 bit pattern
typedef __attribute__((ext_vector_type(8))) short bf16x8;
typedef __attribute__((ext_vector_type(4))) float f32x4;

__device__ __forceinline__ float bf2f(u16 u) {
  union { unsigned int i; float f; } v; v.i = ((unsigned int)u) << 16; return v.f;
}
__device__ __forceinline__ u16 f2bf(float f) {
  union { float f; unsigned int i; } v; v.f = f;
  unsigned int r = v.i + 0x7fffu + ((v.i >> 16) & 1u);  // round-nearest-even
  return (u16)(r >> 16);
}

// ---------------- RMSNorm: one block per row of 512 ----------------
template <int IN_BF16>
__global__ __launch_bounds__(256) void rmsnorm_k(const void* __restrict__ xv,
                                                 const float* __restrict__ w,
                                                 u16* __restrict__ out) {
  int row = blockIdx.x;
  int tid = threadIdx.x;
  float x0, x1;
  if (IN_BF16) {
    const u16* xr = (const u16*)xv + (size_t)row * D_;
    x0 = bf2f(xr[tid]); x1 = bf2f(xr[tid + 256]);
  } else {
    const float* xr = (const float*)xv + (size_t)row * D_;
    x0 = xr[tid]; x1 = xr[tid + 256];
  }
  float s = x0 * x0 + x1 * x1;
#pragma unroll
  for (int off = 32; off >= 1; off >>= 1) s += __shfl_xor(s, off, 64);
  __shared__ float red[4];
  int lane = tid & 63, wid = tid >> 6;
  if (lane == 0) red[wid] = s;
  __syncthreads();
  float tot = red[0] + red[1] + red[2] + red[3];
  float inv = rsqrtf(tot * (1.0f / D_) + 1e-6f);
  u16* orow = out + (size_t)row * D_;
  orow[tid]       = f2bf(x0 * inv * w[tid]);
  orow[tid + 256] = f2bf(x1 * inv * w[tid + 256]);
}

// ------------- Generic GEMM, B-transposed form (fp32 VALU) -------------
template <int RELU, int RMODE, int OF32>
__global__ __launch_bounds__(256) void gemm_bt_k(const u16* __restrict__ A,
                                                 const float* __restrict__ W,
                                                 const void* __restrict__ Rv,
                                                 void* __restrict__ Cv,
                                                 int M, int N, int K) {
  __shared__ float As[16][65];
  __shared__ float Ws[16][65];
  int tid = threadIdx.x;
  int m0 = blockIdx.y * 64, n0 = blockIdx.x * 64;
  int r  = tid >> 2;
  int c4 = (tid & 3) * 4;
  int tx = tid & 15, ty = tid >> 4;
  float acc[4][4] = {};
  for (int k0 = 0; k0 < K; k0 += 16) {
    const u16*   ap = A + (size_t)(m0 + r) * K + (k0 + c4);
    const float* wp = W + (size_t)(n0 + r) * K + (k0 + c4);
    uint2  av = *(const uint2*)ap;
    float4 wv = *(const float4*)wp;
    As[c4 + 0][r] = bf2f((u16)(av.x & 0xffffu));
    As[c4 + 1][r] = bf2f((u16)(av.x >> 16));
    As[c4 + 2][r] = bf2f((u16)(av.y & 0xffffu));
    As[c4 + 3][r] = bf2f((u16)(av.y >> 16));
    Ws[c4 + 0][r] = wv.x;
    Ws[c4 + 1][r] = wv.y;
    Ws[c4 + 2][r] = wv.z;
    Ws[c4 + 3][r] = wv.w;
    __syncthreads();
#pragma unroll
    for (int kk = 0; kk < 16; kk++) {
      float a[4], b[4];
#pragma unroll
      for (int i = 0; i < 4; i++) a[i] = As[kk][ty * 4 + i];
#pragma unroll
      for (int j = 0; j < 4; j++) b[j] = Ws[kk][tx * 4 + j];
#pragma unroll
      for (int i = 0; i < 4; i++)
#pragma unroll
        for (int j = 0; j < 4; j++) acc[i][j] += a[i] * b[j];
    }
    __syncthreads();
  }
#pragma unroll
  for (int i = 0; i < 4; i++) {
    size_t base = (size_t)(m0 + ty * 4 + i) * N + (n0 + tx * 4);
#pragma unroll
    for (int j = 0; j < 4; j++) {
      float v = acc[i][j];
      if (RELU) v = fmaxf(v, 0.0f);
      if (RMODE == 1) v += ((const float*)Rv)[base + j];
      if (RMODE == 2) v += bf2f(((const u16*)Rv)[base + j]);
      if (OF32) ((float*)Cv)[base + j] = v;
      else      ((u16*)Cv)[base + j]   = f2bf(v);
    }
  }
}

// ------------- MFMA flash attention -------------
// Block: 64 q-rows of one (b,h); 4 waves, each owns 16 q-rows.
// K-loop over 32-key tiles. QK^T and PV via mfma_f32_16x16x32_bf16.
// C-layout: row = quad*4+reg, col = lane&15. A-layout: m = lane&15, k = quad*8+j.
__global__ __launch_bounds__(256) void attn_mfma_k(const u16* __restrict__ Q,
                                                   const u16* __restrict__ K,
                                                   const u16* __restrict__ V,
                                                   const float* __restrict__ bias,
                                                   u16* __restrict__ ctx) {
  int tid = threadIdx.x;
  int w = tid >> 6, lane = tid & 63;
  int quad = lane >> 4, l16 = lane & 15;
  int h = blockIdx.y, b = blockIdx.z;
  int q0 = blockIdx.x * 64;

  __shared__ __align__(16) u16 Ks[32][72];      // [key][dim], pad 64->72
  __shared__ __align__(16) u16 Vt[64][40];      // [dim][key], pad 32->40
  __shared__ __align__(16) u16 Pl[4][16][40];   // per-wave P, [q][key], pad 32->40

  // Q fragments (held whole kernel): A[m=l16][k=quad*8+j], two 32-dim chunks
  size_t qbase = ((size_t)(b * S_) + q0 + w * 16 + l16) * D_ + h * HD_;
  bf16x8 qf0 = *(const bf16x8*)(Q + qbase + quad * 8);
  bf16x8 qf1 = *(const bf16x8*)(Q + qbase + 32 + quad * 8);

  float mr[4], lr[4];
  f32x4 Oacc[4];
#pragma unroll
  for (int r = 0; r < 4; r++) { mr[r] = -1e30f; lr[r] = 0.0f; }
#pragma unroll
  for (int nt = 0; nt < 4; nt++) Oacc[nt] = (f32x4)(0.0f);

  const float* bp = bias + (((size_t)(b * H_ + h) * S_) + q0 + w * 16) * S_;

  int skey = tid >> 3;         // 0..31
  int sd8  = (tid & 7) * 8;    // 0,8,...,56

  for (int kt = 0; kt < S_; kt += 32) {
    __syncthreads();
    size_t kb = ((size_t)(b * S_) + kt + skey) * D_ + h * HD_ + sd8;
    bf16x8 kv = *(const bf16x8*)(K + kb);
    *(bf16x8*)(&Ks[skey][sd8]) = kv;
    bf16x8 vv = *(const bf16x8*)(V + kb);
#pragma unroll
    for (int i = 0; i < 8; i++) Vt[sd8 + i][skey] = (u16)((short*)&vv)[i];
    __syncthreads();

    // S = Q K^T + bias for 32 keys (two 16-key halves)
    f32x4 s1 = (f32x4)(0.0f), s2 = (f32x4)(0.0f);
    {
      bf16x8 kf;
      kf = *(const bf16x8*)(&Ks[l16][quad * 8]);
      s1 = __builtin_amdgcn_mfma_f32_16x16x32_bf16(qf0, kf, s1, 0, 0, 0);
      kf = *(const bf16x8*)(&Ks[l16][32 + quad * 8]);
      s1 = __builtin_amdgcn_mfma_f32_16x16x32_bf16(qf1, kf, s1, 0, 0, 0);
      kf = *(const bf16x8*)(&Ks[16 + l16][quad * 8]);
      s2 = __builtin_amdgcn_mfma_f32_16x16x32_bf16(qf0, kf, s2, 0, 0, 0);
      kf = *(const bf16x8*)(&Ks[16 + l16][32 + quad * 8]);
      s2 = __builtin_amdgcn_mfma_f32_16x16x32_bf16(qf1, kf, s2, 0, 0, 0);
    }
#pragma unroll
    for (int r = 0; r < 4; r++) {
      const float* bpr = bp + (size_t)(quad * 4 + r) * S_ + kt;
      s1[r] += bpr[l16];
      s2[r] += bpr[16 + l16];
    }
    // online softmax (per-row state; rows live in this quad's 16 lanes)
#pragma unroll
    for (int r = 0; r < 4; r++) {
      float t = fmaxf(s1[r], s2[r]);
      t = fmaxf(t, __shfl_xor(t, 1, 64));
      t = fmaxf(t, __shfl_xor(t, 2, 64));
      t = fmaxf(t, __shfl_xor(t, 4, 64));
      t = fmaxf(t, __shfl_xor(t, 8, 64));
      float mn = fmaxf(mr[r], t);
      float alpha = __expf(mr[r] - mn);
      float p1 = __expf(s1[r] - mn);
      float p2 = __expf(s2[r] - mn);
      float rs = p1 + p2;
      rs += __shfl_xor(rs, 1, 64);
      rs += __shfl_xor(rs, 2, 64);
      rs += __shfl_xor(rs, 4, 64);
      rs += __shfl_xor(rs, 8, 64);
      lr[r] = lr[r] * alpha + rs;
      mr[r] = mn;
#pragma unroll
      for (int nt = 0; nt < 4; nt++) Oacc[nt][r] *= alpha;
      Pl[w][quad * 4 + r][l16]      = f2bf(p1);
      Pl[w][quad * 4 + r][16 + l16] = f2bf(p2);
    }
    // P: C-layout -> A-layout via wave-local LDS round-trip
    bf16x8 pf = *(const bf16x8*)(&Pl[w][l16][quad * 8]);
    // O += P V  (V^T staged: B[k=key][n=dim] read contiguous from Vt[dim][key])
#pragma unroll
    for (int nt = 0; nt < 4; nt++) {
      bf16x8 vf = *(const bf16x8*)(&Vt[nt * 16 + l16][quad * 8]);
      Oacc[nt] = __builtin_amdgcn_mfma_f32_16x16x32_bf16(pf, vf, Oacc[nt], 0, 0, 0);
    }
  }

  // epilogue: O /= l, write ctx (C-layout rows)
  size_t obase = ((size_t)(b * S_) + q0 + w * 16) * D_ + h * HD_;
#pragma unroll
  for (int r = 0; r < 4; r++) {
    float inv = 1.0f / lr[r];
    int qr = quad * 4 + r;
#pragma unroll
    for (int nt = 0; nt < 4; nt++) {
      ctx[obase + (size_t)qr * D_ + nt * 16 + l16] = f2bf(Oacc[nt][r] * inv);
    }
  }
}

extern "C" void kernel_launch(void* const* d_in, const int* in_sizes, int n_in,
                              void* d_out, int out_size, void* d_ws, size_t ws_size,
                              hipStream_t stream) {
  const float* Wk   = (const float*)d_in[0];  // primals_1 [D,D] -> K proj
  const float* Wo   = (const float*)d_in[1];  // primals_2 [D,D] -> out proj
  const float* Wq   = (const float*)d_in[2];  // primals_3 [D,D] -> Q proj
  const float* Wv   = (const float*)d_in[3];  // primals_4 [D,D] -> V proj
  const float* g1   = (const float*)d_in[4];  // primals_5 [D]
  const float* Wf1  = (const float*)d_in[5];  // primals_6 [F,D]
  const float* Wf2  = (const float*)d_in[6];  // primals_7 [D,F]
  const float* g2   = (const float*)d_in[7];  // primals_8 [D]
  const float* X    = (const float*)d_in[8];  // primals_9 [B,S,D] fp32
  const float* bias = (const float*)d_in[9];  // primals_10 [B,H,S,S] fp32
  float* out = (float*)d_out;

  const size_t MD = (size_t)B_ * S_ * D_;
  u16* h   = (u16*)d_ws;   // buf0: h, later h2
  u16* q   = h + MD;       // buf1
  u16* k   = q + MD;       // buf2: k, later x1
  u16* v   = k + MD;       // buf3
  u16* ctx = v + MD;       // buf4: ctx, later ff chunk
  u16* x1  = k;
  u16* h2  = h;
  u16* ff  = ctx;

  dim3 blk(256);
  const int M = B_ * S_;

  rmsnorm_k<0><<<M, blk, 0, stream>>>(X, g1, h);

  dim3 g512(D_ / 64, M / 64);
  gemm_bt_k<0, 0, 0><<<g512, blk, 0, stream>>>(h, Wq, nullptr, q, M, D_, D_);
  gemm_bt_k<0, 0, 0><<<g512, blk, 0, stream>>>(h, Wk, nullptr, k, M, D_, D_);
  gemm_bt_k<0, 0, 0><<<g512, blk, 0, stream>>>(h, Wv, nullptr, v, M, D_, D_);

  dim3 ga(S_ / 64, H_, B_);
  attn_mfma_k<<<ga, blk, 0, stream>>>(q, k, v, bias, ctx);

  gemm_bt_k<0, 1, 0><<<g512, blk, 0, stream>>>(ctx, Wo, X, x1, M, D_, D_);

  rmsnorm_k<1><<<M, blk, 0, stream>>>(x1, g2, h2);

  const int MC = M / 4;  // 2048
  dim3 gff1(F_ / 64, MC / 64);
  dim3 gff2(D_ / 64, MC / 64);
  for (int c = 0; c < 4; c++) {
    const u16* h2c = h2 + (size_t)c * MC * D_;
    const u16* x1c = x1 + (size_t)c * MC * D_;
    float*     oc  = out + (size_t)c * MC * D_;
    gemm_bt_k<1, 0, 0><<<gff1, blk, 0, stream>>>(h2c, Wf1, nullptr, ff, MC, F_, D_);
    gemm_bt_k<0, 2, 1><<<gff2, blk, 0, stream>>>(ff, Wf2, x1c, oc, MC, D_, F_);
  }
}

// Round 4
// 605.159 us; speedup vs baseline: 8.8918x; 2.8618x over previous
//
#include <hip/hip_runtime.h>

#define B_ 8
#define S_ 1024
#define D_ 512
#define H_ 8
#define HD_ 64
#define F_ 2048

typedef unsigned short u16;  // bf16 bit pattern
typedef __attribute__((ext_vector_type(8))) short bf16x8;
typedef __attribute__((ext_vector_type(4))) float f32x4;

__device__ __forceinline__ float bf2f(u16 u) {
  union { unsigned int i; float f; } v; v.i = ((unsigned int)u) << 16; return v.f;
}
__device__ __forceinline__ u16 f2bf(float f) {
  union { float f; unsigned int i; } v; v.f = f;
  unsigned int r = v.i + 0x7fffu + ((v.i >> 16) & 1u);  // round-nearest-even
  return (u16)(r >> 16);
}

__device__ __forceinline__ void gl2lds16(const u16* g, u16* lds) {
  __builtin_amdgcn_global_load_lds(
      (const __attribute__((address_space(1))) unsigned int*)g,
      (__attribute__((address_space(3))) unsigned int*)lds, 16, 0, 0);
}

// ---------------- weight fp32 -> bf16 conversion ----------------
// Regions (elems): Wk 262144 | Wo 262144 | Wq 262144 | Wv 262144 | Wf1 1048576 | Wf2 1048576
__global__ __launch_bounds__(256) void cvt_w_k(const float* __restrict__ w0, const float* __restrict__ w1,
                                               const float* __restrict__ w2, const float* __restrict__ w3,
                                               const float* __restrict__ w4, const float* __restrict__ w5,
                                               u16* __restrict__ dst) {
  size_t gid = (size_t)blockIdx.x * 256 + threadIdx.x;
  size_t e0 = gid * 4;
  const float* src; size_t loc;
  if      (e0 <  262144) { src = w0; loc = e0; }
  else if (e0 <  524288) { src = w1; loc = e0 -  262144; }
  else if (e0 <  786432) { src = w2; loc = e0 -  524288; }
  else if (e0 < 1048576) { src = w3; loc = e0 -  786432; }
  else if (e0 < 2097152) { src = w4; loc = e0 - 1048576; }
  else                   { src = w5; loc = e0 - 2097152; }
  float4 v = *(const float4*)(src + loc);
  ushort4 o; o.x = f2bf(v.x); o.y = f2bf(v.y); o.z = f2bf(v.z); o.w = f2bf(v.w);
  *(ushort4*)(dst + e0) = o;
}

// ---------------- RMSNorm: one block per row of 512 ----------------
template <int IN_BF16>
__global__ __launch_bounds__(256) void rmsnorm_k(const void* __restrict__ xv,
                                                 const float* __restrict__ w,
                                                 u16* __restrict__ out) {
  int row = blockIdx.x;
  int tid = threadIdx.x;
  float x0, x1;
  if (IN_BF16) {
    const u16* xr = (const u16*)xv + (size_t)row * D_;
    x0 = bf2f(xr[tid]); x1 = bf2f(xr[tid + 256]);
  } else {
    const float* xr = (const float*)xv + (size_t)row * D_;
    x0 = xr[tid]; x1 = xr[tid + 256];
  }
  float s = x0 * x0 + x1 * x1;
#pragma unroll
  for (int off = 32; off >= 1; off >>= 1) s += __shfl_xor(s, off, 64);
  __shared__ float red[4];
  int lane = tid & 63, wid = tid >> 6;
  if (lane == 0) red[wid] = s;
  __syncthreads();
  float tot = red[0] + red[1] + red[2] + red[3];
  float inv = rsqrtf(tot * (1.0f / D_) + 1e-6f);
  u16* orow = out + (size_t)row * D_;
  orow[tid]       = f2bf(x0 * inv * w[tid]);
  orow[tid + 256] = f2bf(x1 * inv * w[tid + 256]);
}

// ------------- MFMA GEMM (m97 structure), B-transposed form -------------
// C[m,n] = resid + act( sum_k A[m,k] * W[n,k] ), A:[M,K] bf16, W:[N,K] bf16
// 128x128 tile, BK=32, 4 waves in 2x2, each wave 64x64 via 4x4 mfma_16x16x32.
// Staging via global_load_lds width=16; XOR swizzle on 16B k-chunks
// (applied on the GLOBAL address side; LDS dest stays lane-contiguous).
// RMODE: 0 none, 1 fp32 residual, 2 bf16 residual. OF32: fp32 out.
template <int RELU, int RMODE, int OF32>
__global__ __launch_bounds__(256) void gemm_mfma_k(const u16* __restrict__ A,
                                                   const u16* __restrict__ W,
                                                   const void* __restrict__ Rv,
                                                   void* __restrict__ Cv,
                                                   int M, int N, int K) {
  __shared__ __align__(16) u16 As[128 * 32];
  __shared__ __align__(16) u16 Bs[128 * 32];
  int tid = threadIdx.x;
  int w = tid >> 6, l = tid & 63;
  int quad = l >> 4, l16 = l & 15;
  int m0 = blockIdx.y * 128, n0 = blockIdx.x * 128;
  int wr = (w >> 1) * 64, wc = (w & 1) * 64;

  // staging: chunk = w*2+t covers LDS bytes [chunk*1024, +1024); lane l -> +l*16
  // row = chunk*16 + (l>>2); stored k-chunk c' = l&3 holds logical c = c' ^ (row&3)
  int c_sw = (l & 3) ^ ((l >> 2) & 3);
  int r_in = l >> 2;
  // reader swizzle: logical chunk quad at row (..+l16) is stored at quad ^ (l16&3)
  int swz = quad ^ (l16 & 3);

  f32x4 acc[4][4];
#pragma unroll
  for (int i = 0; i < 4; i++)
#pragma unroll
    for (int j = 0; j < 4; j++) acc[i][j] = (f32x4)(0.0f);

  for (int k0 = 0; k0 < K; k0 += 32) {
    __syncthreads();
#pragma unroll
    for (int t = 0; t < 2; t++) {
      int chunk = w * 2 + t;
      int row = chunk * 16 + r_in;
      gl2lds16(A + (size_t)(m0 + row) * K + k0 + c_sw * 8, As + chunk * 512);
      gl2lds16(W + (size_t)(n0 + row) * K + k0 + c_sw * 8, Bs + chunk * 512);
    }
    __syncthreads();
    bf16x8 af[4], bf[4];
#pragma unroll
    for (int i = 0; i < 4; i++)
      af[i] = *(const bf16x8*)(As + (wr + i * 16 + l16) * 32 + swz * 8);
#pragma unroll
    for (int j = 0; j < 4; j++)
      bf[j] = *(const bf16x8*)(Bs + (wc + j * 16 + l16) * 32 + swz * 8);
#pragma unroll
    for (int i = 0; i < 4; i++)
#pragma unroll
      for (int j = 0; j < 4; j++)
        acc[i][j] = __builtin_amdgcn_mfma_f32_16x16x32_bf16(af[i], bf[j], acc[i][j], 0, 0, 0);
  }

  // epilogue: D row = (A m) = wr+i*16+quad*4+r, col = (B n) = wc+j*16+l16
#pragma unroll
  for (int i = 0; i < 4; i++)
#pragma unroll
    for (int r = 0; r < 4; r++) {
      int mrow = m0 + wr + i * 16 + quad * 4 + r;
      size_t base = (size_t)mrow * N + n0 + wc + l16;
#pragma unroll
      for (int j = 0; j < 4; j++) {
        float v = acc[i][j][r];
        if (RELU) v = fmaxf(v, 0.0f);
        if (RMODE == 1) v += ((const float*)Rv)[base + j * 16];
        if (RMODE == 2) v += bf2f(((const u16*)Rv)[base + j * 16]);
        if (OF32) ((float*)Cv)[base + j * 16] = v;
        else      ((u16*)Cv)[base + j * 16]   = f2bf(v);
      }
    }
}

// ------------- MFMA flash attention (round-3, verified) -------------
__global__ __launch_bounds__(256) void attn_mfma_k(const u16* __restrict__ Q,
                                                   const u16* __restrict__ K,
                                                   const u16* __restrict__ V,
                                                   const float* __restrict__ bias,
                                                   u16* __restrict__ ctx) {
  int tid = threadIdx.x;
  int w = tid >> 6, lane = tid & 63;
  int quad = lane >> 4, l16 = lane & 15;
  int h = blockIdx.y, b = blockIdx.z;
  int q0 = blockIdx.x * 64;

  __shared__ __align__(16) u16 Ks[32][72];
  __shared__ __align__(16) u16 Vt[64][40];
  __shared__ __align__(16) u16 Pl[4][16][40];

  size_t qbase = ((size_t)(b * S_) + q0 + w * 16 + l16) * D_ + h * HD_;
  bf16x8 qf0 = *(const bf16x8*)(Q + qbase + quad * 8);
  bf16x8 qf1 = *(const bf16x8*)(Q + qbase + 32 + quad * 8);

  float mr[4], lr[4];
  f32x4 Oacc[4];
#pragma unroll
  for (int r = 0; r < 4; r++) { mr[r] = -1e30f; lr[r] = 0.0f; }
#pragma unroll
  for (int nt = 0; nt < 4; nt++) Oacc[nt] = (f32x4)(0.0f);

  const float* bp = bias + (((size_t)(b * H_ + h) * S_) + q0 + w * 16) * S_;

  int skey = tid >> 3;
  int sd8  = (tid & 7) * 8;

  for (int kt = 0; kt < S_; kt += 32) {
    __syncthreads();
    size_t kb = ((size_t)(b * S_) + kt + skey) * D_ + h * HD_ + sd8;
    bf16x8 kv = *(const bf16x8*)(K + kb);
    *(bf16x8*)(&Ks[skey][sd8]) = kv;
    bf16x8 vv = *(const bf16x8*)(V + kb);
#pragma unroll
    for (int i = 0; i < 8; i++) Vt[sd8 + i][skey] = (u16)((short*)&vv)[i];
    __syncthreads();

    f32x4 s1 = (f32x4)(0.0f), s2 = (f32x4)(0.0f);
    {
      bf16x8 kf;
      kf = *(const bf16x8*)(&Ks[l16][quad * 8]);
      s1 = __builtin_amdgcn_mfma_f32_16x16x32_bf16(qf0, kf, s1, 0, 0, 0);
      kf = *(const bf16x8*)(&Ks[l16][32 + quad * 8]);
      s1 = __builtin_amdgcn_mfma_f32_16x16x32_bf16(qf1, kf, s1, 0, 0, 0);
      kf = *(const bf16x8*)(&Ks[16 + l16][quad * 8]);
      s2 = __builtin_amdgcn_mfma_f32_16x16x32_bf16(qf0, kf, s2, 0, 0, 0);
      kf = *(const bf16x8*)(&Ks[16 + l16][32 + quad * 8]);
      s2 = __builtin_amdgcn_mfma_f32_16x16x32_bf16(qf1, kf, s2, 0, 0, 0);
    }
#pragma unroll
    for (int r = 0; r < 4; r++) {
      const float* bpr = bp + (size_t)(quad * 4 + r) * S_ + kt;
      s1[r] += bpr[l16];
      s2[r] += bpr[16 + l16];
    }
#pragma unroll
    for (int r = 0; r < 4; r++) {
      float t = fmaxf(s1[r], s2[r]);
      t = fmaxf(t, __shfl_xor(t, 1, 64));
      t = fmaxf(t, __shfl_xor(t, 2, 64));
      t = fmaxf(t, __shfl_xor(t, 4, 64));
      t = fmaxf(t, __shfl_xor(t, 8, 64));
      float mn = fmaxf(mr[r], t);
      float alpha = __expf(mr[r] - mn);
      float p1 = __expf(s1[r] - mn);
      float p2 = __expf(s2[r] - mn);
      float rs = p1 + p2;
      rs += __shfl_xor(rs, 1, 64);
      rs += __shfl_xor(rs, 2, 64);
      rs += __shfl_xor(rs, 4, 64);
      rs += __shfl_xor(rs, 8, 64);
      lr[r] = lr[r] * alpha + rs;
      mr[r] = mn;
#pragma unroll
      for (int nt = 0; nt < 4; nt++) Oacc[nt][r] *= alpha;
      Pl[w][quad * 4 + r][l16]      = f2bf(p1);
      Pl[w][quad * 4 + r][16 + l16] = f2bf(p2);
    }
    bf16x8 pf = *(const bf16x8*)(&Pl[w][l16][quad * 8]);
#pragma unroll
    for (int nt = 0; nt < 4; nt++) {
      bf16x8 vf = *(const bf16x8*)(&Vt[nt * 16 + l16][quad * 8]);
      Oacc[nt] = __builtin_amdgcn_mfma_f32_16x16x32_bf16(pf, vf, Oacc[nt], 0, 0, 0);
    }
  }

  size_t obase = ((size_t)(b * S_) + q0 + w * 16) * D_ + h * HD_;
#pragma unroll
  for (int r = 0; r < 4; r++) {
    float inv = 1.0f / lr[r];
    int qr = quad * 4 + r;
#pragma unroll
    for (int nt = 0; nt < 4; nt++) {
      ctx[obase + (size_t)qr * D_ + nt * 16 + l16] = f2bf(Oacc[nt][r] * inv);
    }
  }
}

extern "C" void kernel_launch(void* const* d_in, const int* in_sizes, int n_in,
                              void* d_out, int out_size, void* d_ws, size_t ws_size,
                              hipStream_t stream) {
  const float* Wk   = (const float*)d_in[0];  // primals_1 [D,D] -> K proj
  const float* Wo   = (const float*)d_in[1];  // primals_2 [D,D] -> out proj
  const float* Wq   = (const float*)d_in[2];  // primals_3 [D,D] -> Q proj
  const float* Wv   = (const float*)d_in[3];  // primals_4 [D,D] -> V proj
  const float* g1   = (const float*)d_in[4];  // primals_5 [D]
  const float* Wf1  = (const float*)d_in[5];  // primals_6 [F,D]
  const float* Wf2  = (const float*)d_in[6];  // primals_7 [D,F]
  const float* g2   = (const float*)d_in[7];  // primals_8 [D]
  const float* X    = (const float*)d_in[8];  // primals_9 [B,S,D] fp32
  const float* bias = (const float*)d_in[9];  // primals_10 [B,H,S,S] fp32
  float* out = (float*)d_out;

  const size_t MD = (size_t)B_ * S_ * D_;      // 4,194,304 elems / slot
  const size_t WB = 3145728;                   // total bf16 weight elems
  // ws layout (u16 elems): [wbf 3.14M][A][B][C][D][E][F] slots of MD each = 56.6 MB
  u16* wbf  = (u16*)d_ws;
  u16* Wkb  = wbf;            // 262144
  u16* Wob  = wbf +  262144;
  u16* Wqb  = wbf +  524288;
  u16* Wvb  = wbf +  786432;
  u16* Wf1b = wbf + 1048576;  // 1048576
  u16* Wf2b = wbf + 2097152;  // 1048576
  u16* slot = wbf + WB;
  u16* h    = slot;            // A: h, later x1
  u16* q    = slot + MD;       // B: q, later h2
  u16* k    = slot + 2 * MD;   // C: k, later ff[0:]
  u16* v    = slot + 3 * MD;   // D
  u16* ctx  = slot + 4 * MD;   // E
  u16* x1   = h;
  u16* h2   = q;
  u16* ff   = k;               // spans C..F (4 slots = 8192*2048 elems)

  dim3 blk(256);
  const int M = B_ * S_;

  // 0. weights -> bf16
  cvt_w_k<<<3072, blk, 0, stream>>>(Wk, Wo, Wq, Wv, Wf1, Wf2, wbf);

  // 1. h = rmsnorm(x, g1)
  rmsnorm_k<0><<<M, blk, 0, stream>>>(X, g1, h);

  // 2. q/k/v = h @ W^T
  dim3 g512(D_ / 128, M / 128);   // (4, 64)
  gemm_mfma_k<0, 0, 0><<<g512, blk, 0, stream>>>(h, Wqb, nullptr, q, M, D_, D_);
  gemm_mfma_k<0, 0, 0><<<g512, blk, 0, stream>>>(h, Wkb, nullptr, k, M, D_, D_);
  gemm_mfma_k<0, 0, 0><<<g512, blk, 0, stream>>>(h, Wvb, nullptr, v, M, D_, D_);

  // 3. ctx = softmax(q k^T + bias) v
  dim3 ga(S_ / 64, H_, B_);
  attn_mfma_k<<<ga, blk, 0, stream>>>(q, k, v, bias, ctx);

  // 4. x1 = x + ctx @ Wo^T (fp32 residual, bf16 out)
  gemm_mfma_k<0, 1, 0><<<g512, blk, 0, stream>>>(ctx, Wob, X, x1, M, D_, D_);

  // 5. h2 = rmsnorm(x1, g2)
  rmsnorm_k<1><<<M, blk, 0, stream>>>(x1, g2, h2);

  // 6. ff = relu(h2 @ Wf1^T)
  dim3 gff1(F_ / 128, M / 128);   // (16, 64)
  gemm_mfma_k<1, 0, 0><<<gff1, blk, 0, stream>>>(h2, Wf1b, nullptr, ff, M, F_, D_);

  // 7. out = x1 + ff @ Wf2^T (bf16 residual, fp32 out)
  gemm_mfma_k<0, 2, 1><<<g512, blk, 0, stream>>>(ff, Wf2b, x1, out, M, D_, F_);
}

// Round 5
// 580.271 us; speedup vs baseline: 9.2731x; 1.0429x over previous
//
#include <hip/hip_runtime.h>

#define B_ 8
#define S_ 1024
#define D_ 512
#define H_ 8
#define HD_ 64
#define F_ 2048

typedef unsigned short u16;  // bf16 bit pattern
typedef __attribute__((ext_vector_type(8))) short bf16x8;
typedef __attribute__((ext_vector_type(4))) float f32x4;

__device__ __forceinline__ float bf2f(u16 u) {
  union { unsigned int i; float f; } v; v.i = ((unsigned int)u) << 16; return v.f;
}
__device__ __forceinline__ u16 f2bf(float f) {
  union { float f; unsigned int i; } v; v.f = f;
  unsigned int r = v.i + 0x7fffu + ((v.i >> 16) & 1u);  // round-nearest-even
  return (u16)(r >> 16);
}

__device__ __forceinline__ void gl2lds16(const u16* g, u16* lds) {
  __builtin_amdgcn_global_load_lds(
      (const __attribute__((address_space(1))) unsigned int*)g,
      (__attribute__((address_space(3))) unsigned int*)lds, 16, 0, 0);
}

// ---------------- weight fp32 -> bf16 conversion ----------------
// dst regions (elems): [Wq 262144 | Wk 262144 | Wv 262144 | Wo 262144 | Wf1 1048576 | Wf2 1048576]
// (Wq,Wk,Wv contiguous => fused qkv weight [1536,512])
__global__ __launch_bounds__(256) void cvt_w_k(const float* __restrict__ wq, const float* __restrict__ wk,
                                               const float* __restrict__ wv, const float* __restrict__ wo,
                                               const float* __restrict__ wf1, const float* __restrict__ wf2,
                                               u16* __restrict__ dst) {
  size_t gid = (size_t)blockIdx.x * 256 + threadIdx.x;
  size_t e0 = gid * 4;
  const float* src; size_t loc;
  if      (e0 <  262144) { src = wq;  loc = e0; }
  else if (e0 <  524288) { src = wk;  loc = e0 -  262144; }
  else if (e0 <  786432) { src = wv;  loc = e0 -  524288; }
  else if (e0 < 1048576) { src = wo;  loc = e0 -  786432; }
  else if (e0 < 2097152) { src = wf1; loc = e0 - 1048576; }
  else                   { src = wf2; loc = e0 - 2097152; }
  float4 v = *(const float4*)(src + loc);
  ushort4 o; o.x = f2bf(v.x); o.y = f2bf(v.y); o.z = f2bf(v.z); o.w = f2bf(v.w);
  *(ushort4*)(dst + e0) = o;
}

// ---------------- RMSNorm: one block per row of 512 ----------------
template <int IN_BF16>
__global__ __launch_bounds__(256) void rmsnorm_k(const void* __restrict__ xv,
                                                 const float* __restrict__ w,
                                                 u16* __restrict__ out) {
  int row = blockIdx.x;
  int tid = threadIdx.x;
  float x0, x1;
  if (IN_BF16) {
    const u16* xr = (const u16*)xv + (size_t)row * D_;
    x0 = bf2f(xr[tid]); x1 = bf2f(xr[tid + 256]);
  } else {
    const float* xr = (const float*)xv + (size_t)row * D_;
    x0 = xr[tid]; x1 = xr[tid + 256];
  }
  float s = x0 * x0 + x1 * x1;
#pragma unroll
  for (int off = 32; off >= 1; off >>= 1) s += __shfl_xor(s, off, 64);
  __shared__ float red[4];
  int lane = tid & 63, wid = tid >> 6;
  if (lane == 0) red[wid] = s;
  __syncthreads();
  float tot = red[0] + red[1] + red[2] + red[3];
  float inv = rsqrtf(tot * (1.0f / D_) + 1e-6f);
  u16* orow = out + (size_t)row * D_;
  orow[tid]       = f2bf(x0 * inv * w[tid]);
  orow[tid + 256] = f2bf(x1 * inv * w[tid + 256]);
}

// ------------- MFMA GEMM (m97 structure), B-transposed form -------------
template <int RELU, int RMODE, int OF32>
__global__ __launch_bounds__(256) void gemm_mfma_k(const u16* __restrict__ A,
                                                   const u16* __restrict__ W,
                                                   const void* __restrict__ Rv,
                                                   void* __restrict__ Cv,
                                                   int M, int N, int K) {
  __shared__ __align__(16) u16 As[128 * 32];
  __shared__ __align__(16) u16 Bs[128 * 32];
  int tid = threadIdx.x;
  int w = tid >> 6, l = tid & 63;
  int quad = l >> 4, l16 = l & 15;
  int m0 = blockIdx.y * 128, n0 = blockIdx.x * 128;
  int wr = (w >> 1) * 64, wc = (w & 1) * 64;

  int c_sw = (l & 3) ^ ((l >> 2) & 3);
  int r_in = l >> 2;
  int swz = quad ^ (l16 & 3);

  f32x4 acc[4][4];
#pragma unroll
  for (int i = 0; i < 4; i++)
#pragma unroll
    for (int j = 0; j < 4; j++) acc[i][j] = (f32x4)(0.0f);

  for (int k0 = 0; k0 < K; k0 += 32) {
    __syncthreads();
#pragma unroll
    for (int t = 0; t < 2; t++) {
      int chunk = w * 2 + t;
      int row = chunk * 16 + r_in;
      gl2lds16(A + (size_t)(m0 + row) * K + k0 + c_sw * 8, As + chunk * 512);
      gl2lds16(W + (size_t)(n0 + row) * K + k0 + c_sw * 8, Bs + chunk * 512);
    }
    __syncthreads();
    bf16x8 af[4], bf[4];
#pragma unroll
    for (int i = 0; i < 4; i++)
      af[i] = *(const bf16x8*)(As + (wr + i * 16 + l16) * 32 + swz * 8);
#pragma unroll
    for (int j = 0; j < 4; j++)
      bf[j] = *(const bf16x8*)(Bs + (wc + j * 16 + l16) * 32 + swz * 8);
#pragma unroll
    for (int i = 0; i < 4; i++)
#pragma unroll
      for (int j = 0; j < 4; j++)
        acc[i][j] = __builtin_amdgcn_mfma_f32_16x16x32_bf16(af[i], bf[j], acc[i][j], 0, 0, 0);
  }

#pragma unroll
  for (int i = 0; i < 4; i++)
#pragma unroll
    for (int r = 0; r < 4; r++) {
      int mrow = m0 + wr + i * 16 + quad * 4 + r;
      size_t base = (size_t)mrow * N + n0 + wc + l16;
#pragma unroll
      for (int j = 0; j < 4; j++) {
        float v = acc[i][j][r];
        if (RELU) v = fmaxf(v, 0.0f);
        if (RMODE == 1) v += ((const float*)Rv)[base + j * 16];
        if (RMODE == 2) v += bf2f(((const u16*)Rv)[base + j * 16]);
        if (OF32) ((float*)Cv)[base + j * 16] = v;
        else      ((u16*)Cv)[base + j * 16]   = f2bf(v);
      }
    }
}

// ------------- V transpose: qkv v-cols -> Vt[b][h][d][s] -------------
__global__ __launch_bounds__(256) void transpose_v_k(const u16* __restrict__ qkv,
                                                     u16* __restrict__ vt) {
  __shared__ u16 T[64][72];  // [dim][key], pad 64->72 (144 B rows, 16-aligned)
  int t = threadIdx.x;
  int s0 = blockIdx.x * 64, h = blockIdx.y, b = blockIdx.z;
  int skey = t >> 3, dch = (t & 7) * 8;
#pragma unroll
  for (int rnd = 0; rnd < 2; rnd++) {
    int s = s0 + skey + rnd * 32;
    bf16x8 vv = *(const bf16x8*)(qkv + ((size_t)(b * S_) + s) * 1536 + 1024 + h * HD_ + dch);
#pragma unroll
    for (int i = 0; i < 8; i++) T[dch + i][skey + rnd * 32] = (u16)((short*)&vv)[i];
  }
  __syncthreads();
  int d = t >> 2, kc = (t & 3) * 16;
  bf16x8 a0 = *(const bf16x8*)(&T[d][kc]);
  bf16x8 a1 = *(const bf16x8*)(&T[d][kc + 8]);
  u16* dst = vt + ((size_t)(b * H_ + h) * HD_ + d) * S_ + s0 + kc;
  *(bf16x8*)dst       = a0;
  *(bf16x8*)(dst + 8) = a1;
}

// ------------- MFMA flash attention v2 -------------
// Block: 64 q-rows of one (b,h); 4 waves x 16 q-rows. 64-key tiles.
// K and pre-transposed V staged via global_load_lds into split 32-elem-row
// buffers with m97 XOR chunk swizzle. 2 barriers / 16 MFMA per wave per tile.
__global__ __launch_bounds__(256) void attn_v2_k(const u16* __restrict__ qkv,
                                                 const u16* __restrict__ vt,
                                                 const float* __restrict__ bias,
                                                 u16* __restrict__ ctx) {
  int tid = threadIdx.x;
  int w = tid >> 6, lane = tid & 63;
  int quad = lane >> 4, l16 = lane & 15;
  int h = blockIdx.y, b = blockIdx.z;
  int q0 = blockIdx.x * 64;

  __shared__ __align__(16) u16 KsA[64 * 32];   // [key][dim 0..31]
  __shared__ __align__(16) u16 KsB[64 * 32];   // [key][dim 32..63]
  __shared__ __align__(16) u16 VsA[64 * 32];   // [dim][key 0..31]
  __shared__ __align__(16) u16 VsB[64 * 32];   // [dim][key 32..63]
  __shared__ __align__(16) u16 Pl[4][16 * 72]; // per-wave P, [q][key], pad 64->72

  // Q fragments: A[m=l16][k=quad*8+j], dims 0..31 / 32..63
  const u16* qrow = qkv + ((size_t)(b * S_) + q0 + w * 16 + l16) * 1536 + h * HD_;
  bf16x8 qf0 = *(const bf16x8*)(qrow + quad * 8);
  bf16x8 qf1 = *(const bf16x8*)(qrow + 32 + quad * 8);

  float mr[4], lr[4];
  f32x4 Oacc[4];
#pragma unroll
  for (int r = 0; r < 4; r++) { mr[r] = -1e30f; lr[r] = 0.0f; }
#pragma unroll
  for (int nt = 0; nt < 4; nt++) Oacc[nt] = (f32x4)(0.0f);

  const float* bpw = bias + ((size_t)((b * H_ + h) * S_) + q0 + w * 16) * S_;

  // staging lane map: each wave stages rows w*16 .. w*16+15 of each buffer
  int srow = w * 16 + (lane >> 2);
  int sc   = lane & 3;
  int slc  = sc ^ (srow & 3);   // logical 16B chunk (global side)
  u16* ldsKA = KsA + w * 512;   // 16 rows * 32 u16
  u16* ldsKB = KsB + w * 512;
  u16* ldsVA = VsA + w * 512;
  u16* ldsVB = VsB + w * 512;

  for (int kt = 0; kt < S_; kt += 64) {
    __syncthreads();
    {
      const u16* krow = qkv + ((size_t)(b * S_) + kt + srow) * 1536 + 512 + h * HD_;
      gl2lds16(krow + slc * 8, ldsKA);
      gl2lds16(krow + 32 + slc * 8, ldsKB);
      const u16* vrow = vt + ((size_t)(b * H_ + h) * HD_ + srow) * S_ + kt;
      gl2lds16(vrow + slc * 8, ldsVA);
      gl2lds16(vrow + 32 + slc * 8, ldsVB);
    }
    __syncthreads();

    // S = Q K^T + bias, 4 groups of 16 keys
    f32x4 sg[4];
#pragma unroll
    for (int g = 0; g < 4; g++) {
      int row = g * 16 + l16;
      int sw = quad ^ (row & 3);
      bf16x8 kf0 = *(const bf16x8*)(KsA + row * 32 + sw * 8);
      bf16x8 kf1 = *(const bf16x8*)(KsB + row * 32 + sw * 8);
      f32x4 a = (f32x4)(0.0f);
      a = __builtin_amdgcn_mfma_f32_16x16x32_bf16(qf0, kf0, a, 0, 0, 0);
      a = __builtin_amdgcn_mfma_f32_16x16x32_bf16(qf1, kf1, a, 0, 0, 0);
      sg[g] = a;
    }
    // bias add + online softmax (rows = quad*4+r)
#pragma unroll
    for (int r = 0; r < 4; r++) {
      size_t bro = (size_t)(quad * 4 + r) * S_ + kt + l16;
      float b0 = bpw[bro];
      float b1 = bpw[bro + 16];
      float b2 = bpw[bro + 32];
      float b3 = bpw[bro + 48];
      float s0 = sg[0][r] + b0, s1 = sg[1][r] + b1, s2 = sg[2][r] + b2, s3 = sg[3][r] + b3;
      float t = fmaxf(fmaxf(s0, s1), fmaxf(s2, s3));
      t = fmaxf(t, __shfl_xor(t, 1, 64));
      t = fmaxf(t, __shfl_xor(t, 2, 64));
      t = fmaxf(t, __shfl_xor(t, 4, 64));
      t = fmaxf(t, __shfl_xor(t, 8, 64));
      float mn = fmaxf(mr[r], t);
      float alpha = __expf(mr[r] - mn);
      float p0 = __expf(s0 - mn), p1 = __expf(s1 - mn);
      float p2 = __expf(s2 - mn), p3 = __expf(s3 - mn);
      float rs = (p0 + p1) + (p2 + p3);
      rs += __shfl_xor(rs, 1, 64);
      rs += __shfl_xor(rs, 2, 64);
      rs += __shfl_xor(rs, 4, 64);
      rs += __shfl_xor(rs, 8, 64);
      lr[r] = lr[r] * alpha + rs;
      mr[r] = mn;
#pragma unroll
      for (int nt = 0; nt < 4; nt++) Oacc[nt][r] *= alpha;
      u16* prow = &Pl[w][(quad * 4 + r) * 72];
      prow[l16]      = f2bf(p0);
      prow[16 + l16] = f2bf(p1);
      prow[32 + l16] = f2bf(p2);
      prow[48 + l16] = f2bf(p3);
    }
    // P: C-layout -> A-layout (wave-local, no barrier needed)
    bf16x8 pf0 = *(const bf16x8*)(&Pl[w][l16 * 72 + quad * 8]);
    bf16x8 pf1 = *(const bf16x8*)(&Pl[w][l16 * 72 + 32 + quad * 8]);
    // O += P V  (B-frag from V^T halves)
#pragma unroll
    for (int nt = 0; nt < 4; nt++) {
      int row = nt * 16 + l16;
      int sw = quad ^ (row & 3);
      bf16x8 vf0 = *(const bf16x8*)(VsA + row * 32 + sw * 8);
      bf16x8 vf1 = *(const bf16x8*)(VsB + row * 32 + sw * 8);
      Oacc[nt] = __builtin_amdgcn_mfma_f32_16x16x32_bf16(pf0, vf0, Oacc[nt], 0, 0, 0);
      Oacc[nt] = __builtin_amdgcn_mfma_f32_16x16x32_bf16(pf1, vf1, Oacc[nt], 0, 0, 0);
    }
  }

  size_t obase = ((size_t)(b * S_) + q0 + w * 16) * D_ + h * HD_;
#pragma unroll
  for (int r = 0; r < 4; r++) {
    float inv = 1.0f / lr[r];
    int qr = quad * 4 + r;
#pragma unroll
    for (int nt = 0; nt < 4; nt++) {
      ctx[obase + (size_t)qr * D_ + nt * 16 + l16] = f2bf(Oacc[nt][r] * inv);
    }
  }
}

extern "C" void kernel_launch(void* const* d_in, const int* in_sizes, int n_in,
                              void* d_out, int out_size, void* d_ws, size_t ws_size,
                              hipStream_t stream) {
  const float* Wk   = (const float*)d_in[0];  // primals_1 [D,D] -> K proj
  const float* Wo   = (const float*)d_in[1];  // primals_2 [D,D] -> out proj
  const float* Wq   = (const float*)d_in[2];  // primals_3 [D,D] -> Q proj
  const float* Wv   = (const float*)d_in[3];  // primals_4 [D,D] -> V proj
  const float* g1   = (const float*)d_in[4];  // primals_5 [D]
  const float* Wf1  = (const float*)d_in[5];  // primals_6 [F,D]
  const float* Wf2  = (const float*)d_in[6];  // primals_7 [D,F]
  const float* g2   = (const float*)d_in[7];  // primals_8 [D]
  const float* X    = (const float*)d_in[8];  // primals_9 [B,S,D] fp32
  const float* bias = (const float*)d_in[9];  // primals_10 [B,H,S,S] fp32
  float* out = (float*)d_out;

  const size_t MD = (size_t)B_ * S_ * D_;       // 4,194,304
  // ws layout (u16 elems):
  // [wbf 3.146M][h 4.19M][qkv 12.58M][vt 4.19M][ctx 4.19M][ff 16.78M] = 90.2 MB
  u16* wbf   = (u16*)d_ws;
  u16* Wqkvb = wbf;               // [1536,512] = Wq|Wk|Wv
  u16* Wob   = wbf +  786432;
  u16* Wf1b  = wbf + 1048576;
  u16* Wf2b  = wbf + 2097152;
  u16* h     = wbf + 3145728;     // h, later h2
  u16* qkv   = h + MD;            // [8192][1536]; later x1
  u16* vtb   = qkv + 3 * MD;      // [B,H,64,S]
  u16* ctx   = vtb + MD;
  u16* ff    = ctx + MD;          // [8192][2048]
  u16* x1    = qkv;
  u16* h2    = h;

  dim3 blk(256);
  const int M = B_ * S_;

  // 0. weights -> bf16 (Wq|Wk|Wv contiguous for fused qkv)
  cvt_w_k<<<3072, blk, 0, stream>>>(Wq, Wk, Wv, Wo, Wf1, Wf2, wbf);

  // 1. h = rmsnorm(x, g1)
  rmsnorm_k<0><<<M, blk, 0, stream>>>(X, g1, h);

  // 2. qkv = h @ Wqkv^T  (M=8192, N=1536, K=512)
  dim3 gqkv(1536 / 128, M / 128);   // (12, 64) = 768 blocks
  gemm_mfma_k<0, 0, 0><<<gqkv, blk, 0, stream>>>(h, Wqkvb, nullptr, qkv, M, 1536, D_);

  // 3. Vt = transpose(v)
  dim3 gt(S_ / 64, H_, B_);
  transpose_v_k<<<gt, blk, 0, stream>>>(qkv, vtb);

  // 4. ctx = softmax(q k^T + bias) v
  dim3 ga(S_ / 64, H_, B_);
  attn_v2_k<<<ga, blk, 0, stream>>>(qkv, vtb, bias, ctx);

  // 5. x1 = x + ctx @ Wo^T (fp32 residual, bf16 out)
  dim3 g512(D_ / 128, M / 128);
  gemm_mfma_k<0, 1, 0><<<g512, blk, 0, stream>>>(ctx, Wob, X, x1, M, D_, D_);

  // 6. h2 = rmsnorm(x1, g2)
  rmsnorm_k<1><<<M, blk, 0, stream>>>(x1, g2, h2);

  // 7. ff = relu(h2 @ Wf1^T)
  dim3 gff1(F_ / 128, M / 128);     // (16, 64)
  gemm_mfma_k<1, 0, 0><<<gff1, blk, 0, stream>>>(h2, Wf1b, nullptr, ff, M, F_, D_);

  // 8. out = x1 + ff @ Wf2^T (bf16 residual, fp32 out)
  gemm_mfma_k<0, 2, 1><<<g512, blk, 0, stream>>>(ff, Wf2b, x1, out, M, D_, F_);
}